// Round 8
// baseline (476.858 us; speedup 1.0000x reference)
//
#include <hip/hip_runtime.h>

typedef float f4 __attribute__((ext_vector_type(4)));

constexpr int NN = 100000;
constexpr int NE = 1600000;
constexpr int SCAN_BLK = 1024;
constexpr int NB = (NN + SCAN_BLK - 1) / SCAN_BLK;    // 98 scan blocks

__device__ __forceinline__ f4 relu_add(f4 a, f4 b) {
    f4 s = a + b;
    s.x = fmaxf(s.x, 0.f);
    s.y = fmaxf(s.y, 0.f);
    s.z = fmaxf(s.z, 0.f);
    s.w = fmaxf(s.w, 0.f);
    return s;
}

// ---------------- fallback path (used only if ws too small) -------------------

__global__ __launch_bounds__(256) void k_init(const float* __restrict__ x,
                                              const float* __restrict__ eps,
                                              float* __restrict__ out) {
    const float s = 1.0f + eps[0];
    const float4* x4 = (const float4*)x;
    float4* o4 = (float4*)out;
    const int total = NN * 16;
    for (int i = blockIdx.x * blockDim.x + threadIdx.x; i < total;
         i += gridDim.x * blockDim.x) {
        float4 v = x4[i];
        v.x *= s; v.y *= s; v.z *= s; v.w *= s;
        o4[i] = v;
    }
}

__global__ __launch_bounds__(256) void k_edges(const float* __restrict__ x,
                                               const int* __restrict__ ei,
                                               const float* __restrict__ ea,
                                               float* __restrict__ out) {
    const int* dst = ei;
    const int* src = ei + NE;
    const float4* ea4 = (const float4*)ea;
    const float4* x4 = (const float4*)x;
    const int total = NE * 16;
    for (int g = blockIdx.x * blockDim.x + threadIdx.x; g < total;
         g += gridDim.x * blockDim.x) {
        const int e = g >> 4;
        const int c = g & 15;
        const int s = src[e];
        const int d = dst[e];
        float4 a  = ea4[g];
        float4 xv = x4[s * 16 + c];
        float* base = out + d * 64 + c * 4;
        atomicAdd(base + 0, fmaxf(xv.x + a.x, 0.0f));
        atomicAdd(base + 1, fmaxf(xv.y + a.y, 0.0f));
        atomicAdd(base + 2, fmaxf(xv.z + a.z, 0.0f));
        atomicAdd(base + 3, fmaxf(xv.w + a.w, 0.0f));
    }
}

__global__ __launch_bounds__(256) void k_linear2(const float* __restrict__ W,
                                                 const float* __restrict__ bias,
                                                 float* __restrict__ out) {
    __shared__ float Ws[64 * 64];
    __shared__ float bs[64];
    for (int i = threadIdx.x; i < 1024; i += 256)
        ((float4*)Ws)[i] = ((const float4*)W)[i];
    if (threadIdx.x < 16)
        ((float4*)bs)[threadIdx.x] = ((const float4*)bias)[threadIdx.x];
    __syncthreads();

    const int l16 = threadIdx.x & 15;
    const int gid = (blockIdx.x * 256 + threadIdx.x) >> 4;
    const float4* Ws4 = (const float4*)Ws;
    float4* out4 = (float4*)out;

    const float4 h4 = out4[gid * 16 + l16];
    float4 o = ((const float4*)bs)[l16];
#pragma unroll
    for (int d = 0; d < 64; ++d) {
        const int q = d >> 2;
        const int r = d & 3;
        float hd;
        if (r == 0)      hd = __shfl(h4.x, q, 16);
        else if (r == 1) hd = __shfl(h4.y, q, 16);
        else if (r == 2) hd = __shfl(h4.z, q, 16);
        else             hd = __shfl(h4.w, q, 16);
        const float4 w = Ws4[d * 16 + l16];
        o.x = fmaf(hd, w.x, o.x);
        o.y = fmaf(hd, w.y, o.y);
        o.z = fmaf(hd, w.z, o.z);
        o.w = fmaf(hd, w.w, o.w);
    }
    out4[gid * 16 + l16] = o;
}

// ---------------- main path ----------------------------------------------------

__global__ __launch_bounds__(256) void k_hist(const int* __restrict__ dst,
                                              int* __restrict__ counts) {
    const int4* d4 = (const int4*)dst;
    const int total = NE / 4;
    for (int i = blockIdx.x * blockDim.x + threadIdx.x; i < total;
         i += gridDim.x * blockDim.x) {
        const int4 d = d4[i];
        atomicAdd(&counts[d.x], 1);
        atomicAdd(&counts[d.y], 1);
        atomicAdd(&counts[d.z], 1);
        atomicAdd(&counts[d.w], 1);
    }
}

__global__ __launch_bounds__(256) void k_scan_block(const int* __restrict__ counts,
                                                    int* __restrict__ offsets,
                                                    int* __restrict__ bsum) {
    __shared__ int sd[256];
    const int t = threadIdx.x;
    const int base = blockIdx.x * SCAN_BLK;
    int c[4];
    int s = 0;
#pragma unroll
    for (int k = 0; k < 4; ++k) {
        const int i = base + t * 4 + k;
        c[k] = (i < NN) ? counts[i] : 0;
        s += c[k];
    }
    sd[t] = s;
    __syncthreads();
#pragma unroll
    for (int off = 1; off < 256; off <<= 1) {
        int v = (t >= off) ? sd[t - off] : 0;
        __syncthreads();
        sd[t] += v;
        __syncthreads();
    }
    int excl = sd[t] - s;
#pragma unroll
    for (int k = 0; k < 4; ++k) {
        const int i = base + t * 4 + k;
        if (i < NN) offsets[i] = excl;
        excl += c[k];
    }
    if (t == 255) bsum[blockIdx.x] = sd[255];
}

__global__ __launch_bounds__(128) void k_scan_sums(const int* __restrict__ bsum,
                                                   int* __restrict__ bsum_ex) {
    __shared__ int sd[128];
    const int t = threadIdx.x;
    const int v = (t < NB) ? bsum[t] : 0;
    sd[t] = v;
    __syncthreads();
#pragma unroll
    for (int off = 1; off < 128; off <<= 1) {
        int u = (t >= off) ? sd[t - off] : 0;
        __syncthreads();
        sd[t] += u;
        __syncthreads();
    }
    bsum_ex[t] = sd[t] - v;
}

__global__ __launch_bounds__(256) void k_scan_add(int* __restrict__ offsets,
                                                  const int* __restrict__ bsum_ex,
                                                  int* __restrict__ cursor) {
    for (int i = blockIdx.x * blockDim.x + threadIdx.x; i < NN;
         i += gridDim.x * blockDim.x) {
        const int v = offsets[i] + bsum_ex[i >> 10];
        offsets[i] = v;
        cursor[i] = v;
    }
    if (blockIdx.x == 0 && threadIdx.x == 0) offsets[NN] = NE;
}

// Edge-order streaming value scatter: ea read is SEQUENTIAL; the randomness
// moves to the (fire-and-forget) 256B row writes into dst-sorted slots.
// One 16-lane group per edge; lane0 claims the slot via int atomic.
__global__ __launch_bounds__(256) void k_scatter_val(const float* __restrict__ x,
                                                     const int* __restrict__ ei,
                                                     const float* __restrict__ ea,
                                                     int* __restrict__ cursor,
                                                     float* __restrict__ vals) {
    const int* dst = ei;
    const int* src = ei + NE;
    const int l16 = threadIdx.x & 15;
    const int gid0 = (blockIdx.x * blockDim.x + threadIdx.x) >> 4;
    const int ngrp = (gridDim.x * blockDim.x) >> 4;
    const f4* x4 = (const f4*)x;
    const f4* ea4 = (const f4*)ea;
    f4* vals4 = (f4*)vals;

    for (int e = gid0; e < NE; e += ngrp) {
        const int d = dst[e];
        const int s = src[e];
        int pos = 0;
        if (l16 == 0) pos = atomicAdd(&cursor[d], 1);
        pos = __shfl(pos, 0, 16);
        const f4 A = ea4[e * 16 + l16];          // streaming (coalesced per group)
        const f4 X = x4[s * 16 + l16];           // L3-resident gather
        const f4 v = relu_add(X, A);
        __builtin_nontemporal_store(v, &vals4[pos * 16 + l16]);
    }
}

// Streaming segmented sum + self-term + fused linear.
// One node per 16-lane group (grid-stride); the group's value rows are a
// CONTIGUOUS byte range [beg*256, end*256) -> pure sequential read.
__global__ __launch_bounds__(256) void k_segsum_lin(const float* __restrict__ x,
                                                    const float* __restrict__ vals,
                                                    const int* __restrict__ offsets,
                                                    const float* __restrict__ epsp,
                                                    const float* __restrict__ W,
                                                    const float* __restrict__ bias,
                                                    float* __restrict__ out) {
    __shared__ float Ws[64 * 64];
    __shared__ float bs[64];
    for (int i = threadIdx.x; i < 1024; i += 256)
        ((float4*)Ws)[i] = ((const float4*)W)[i];
    if (threadIdx.x < 16)
        ((float4*)bs)[threadIdx.x] = ((const float4*)bias)[threadIdx.x];
    __syncthreads();

    const float epsv = 1.0f + epsp[0];
    const int l16 = threadIdx.x & 15;
    const int gid0 = (blockIdx.x * blockDim.x + threadIdx.x) >> 4;
    const int ngrp = (gridDim.x * blockDim.x) >> 4;
    const f4* x4 = (const f4*)x;
    const f4* vals4 = (const f4*)vals;
    const f4* Ws4 = (const f4*)Ws;
    f4* out4 = (f4*)out;

    for (int n = gid0; n < NN; n += ngrp) {
        const int beg = offsets[n];
        const int end = offsets[n + 1];
        f4 acc = {0.f, 0.f, 0.f, 0.f};

        int j = beg;
        for (; j + 4 <= end; j += 4) {           // sequential 256B rows
            const f4 v0 = __builtin_nontemporal_load(&vals4[(j + 0) * 16 + l16]);
            const f4 v1 = __builtin_nontemporal_load(&vals4[(j + 1) * 16 + l16]);
            const f4 v2 = __builtin_nontemporal_load(&vals4[(j + 2) * 16 + l16]);
            const f4 v3 = __builtin_nontemporal_load(&vals4[(j + 3) * 16 + l16]);
            acc += v0 + v1 + v2 + v3;
        }
        for (; j < end; ++j)
            acc += __builtin_nontemporal_load(&vals4[j * 16 + l16]);

        const f4 xs = x4[n * 16 + l16];
        acc.x = fmaf(xs.x, epsv, acc.x);
        acc.y = fmaf(xs.y, epsv, acc.y);
        acc.z = fmaf(xs.z, epsv, acc.z);
        acc.w = fmaf(xs.w, epsv, acc.w);

        // fused linear: o[l16*4+k] = b + sum_d h[d] * W[d][l16*4+k]
        f4 o = ((const f4*)bs)[l16];
#pragma unroll
        for (int d = 0; d < 64; ++d) {
            const int q = d >> 2;
            const int r = d & 3;
            float hd;
            if (r == 0)      hd = __shfl(acc.x, q, 16);
            else if (r == 1) hd = __shfl(acc.y, q, 16);
            else if (r == 2) hd = __shfl(acc.z, q, 16);
            else             hd = __shfl(acc.w, q, 16);
            const f4 w = Ws4[d * 16 + l16];
            o.x = fmaf(hd, w.x, o.x);
            o.y = fmaf(hd, w.y, o.y);
            o.z = fmaf(hd, w.z, o.z);
            o.w = fmaf(hd, w.w, o.w);
        }
        out4[n * 16 + l16] = o;
    }
}

extern "C" void kernel_launch(void* const* d_in, const int* in_sizes, int n_in,
                              void* d_out, int out_size, void* d_ws, size_t ws_size,
                              hipStream_t stream) {
    const float* x   = (const float*)d_in[0];
    const int*   ei  = (const int*)d_in[1];
    const float* ea  = (const float*)d_in[2];
    const float* eps = (const float*)d_in[3];
    const float* W   = (const float*)d_in[4];
    const float* b   = (const float*)d_in[5];
    float* out = (float*)d_out;

    const int* dst = ei;        // edge_index[0]

    // workspace layout: vals first (16B aligned at base)
    float* vals  = (float*)d_ws;           // NE * 64 floats
    int* counts  = (int*)(vals + (size_t)NE * 64);  // NN
    int* offsets = counts + NN;            // NN + 1
    int* cursor  = offsets + NN + 1;       // NN
    int* bsum    = cursor + NN;            // 128
    int* bsum_ex = bsum + 128;             // 128
    const size_t ws_needed = (size_t)NE * 64 * sizeof(float) +
                             (size_t)(3 * NN + 1 + 256) * sizeof(int);

    if (ws_size < ws_needed) {             // insurance: atomic fallback
        k_init<<<2048, 256, 0, stream>>>(x, eps, out);
        k_edges<<<2048, 256, 0, stream>>>(x, ei, ea, out);
        k_linear2<<<NN * 16 / 256, 256, 0, stream>>>(W, b, out);
        return;
    }

    hipMemsetAsync(counts, 0, (size_t)NN * sizeof(int), stream);
    k_hist<<<1024, 256, 0, stream>>>(dst, counts);
    k_scan_block<<<NB, 256, 0, stream>>>(counts, offsets, bsum);
    k_scan_sums<<<1, 128, 0, stream>>>(bsum, bsum_ex);
    k_scan_add<<<256, 256, 0, stream>>>(offsets, bsum_ex, cursor);
    k_scatter_val<<<4096, 256, 0, stream>>>(x, ei, ea, cursor, vals);
    k_segsum_lin<<<2048, 256, 0, stream>>>(x, vals, offsets, eps, W, b, out);
}